// Round 6
// baseline (2005.469 us; speedup 1.0000x reference)
//
#include <hip/hip_runtime.h>
#include <hip/hip_cooperative_groups.h>
#include <cstddef>
#include <cstdint>

namespace cg = cooperative_groups;

// ---------------------------------------------------------------------------
// attention_net_noc: pointer-network decode step.
// R6: R5 with the enum spelling fixed (hipDeviceAttributeMultiprocessorCount
// - lowercase 'p'; R5 never compiled). Queries occupancy, sizes the coop
// grid from the query, CHECKS the launch result, and falls back to an
// 8-dispatch multi-kernel path (same __device__ phase bodies -> identical
// numerics, reproduces R3's 342us) if the coop launch fails.
// ---------------------------------------------------------------------------

constexpr int NJ = 1000000;
constexpr int NM = 500000;
constexpr float NEGV = -1e8f;

constexpr int BLK = 256;
constexpr int NBJ_MAX = 2048;    // fallback job-role blocks (R3 scale)
constexpr int NBM_MAX = 1024;    // fallback machine-role blocks
constexpr int NBT_MAX = NBJ_MAX + NBM_MAX;   // 3072

// ---- workspace layout (float offsets from start of d_ws) ----
constexpr int S_QKJA = 0;    // 16: ja_Wq@g1 + ja_bq
constexpr int S_QK2J = 16;   // 16: aj_Wq@e_js + aj_bq
constexpr int S_QK2M = 32;   // 16: am_Wq@e_js + am_bq
constexpr int S_EJS  = 48;   // 16: E_j[sel_j]
constexpr int S_QKMA = 64;   // 16: ma_Wq@g2 + ma_bq
constexpr int S_LOGPJ = 80;
constexpr int S_SELJ  = 81;  // stored as float (exact, < 2^24)
constexpr int P1J = 96;                       // NBJ_MAX*17 glimpse partials
constexpr int P1M = P1J + NBJ_MAX * 17;       // NBM_MAX*17
constexpr int P2V = P1M + NBM_MAX * 17;       // NBT_MAX argmax vals
constexpr int P2I = P2V + NBT_MAX;
constexpr int P2L = P2I + NBT_MAX;
constexpr size_t E_OFF = 65536;               // float offset of E_j cache
static_assert(P2L + NBT_MAX <= (int)E_OFF, "partials overflow into E cache");

typedef float v2f __attribute__((ext_vector_type(2)));

struct Params {
    const float *jobs, *machines;
    const int *mask;
    const float *jW1, *jb1, *jW2, *jb2;
    const float *mW1, *mb1, *mW2, *mb2;
    const float *aj_Wq, *aj_bq, *aj_Wr, *aj_V;
    const float *am_Wq, *am_bq, *am_Wr, *am_V;
    const float *ja_Wq, *ja_bq, *ja_Wr, *ja_V;
    const float *ma_Wq, *ma_bq, *ma_Wr, *ma_V;
    const float *g1W, *g1b, *g2W, *g2b, *last_j;
    float *S;        // smalls + partials (in ws)
    float *Ej, *Em;  // embedding cache (in ws; used only if CACHE)
    float *out;
    int nbj, nbm;    // role-split block counts (grid must equal nbj+nbm)
};

// ---------------------------------------------------------------------------
// device helpers (numerically identical to R3/R4)
// ---------------------------------------------------------------------------

__device__ __forceinline__ float fast_tanh(float x) {
    float e = __expf(2.0f * x);
    return 1.0f - __fdividef(2.0f, e + 1.0f);
}

__device__ __forceinline__ v2f vbc(float a) { v2f r; r.x = a; r.y = a; return r; }

__device__ __forceinline__ v2f vfma(float w, v2f b, v2f c) {
    return __builtin_elementwise_fma(vbc(w), b, c);
}
__device__ __forceinline__ v2f vfma2(v2f a, v2f b, v2f c) {
    return __builtin_elementwise_fma(a, b, c);
}
__device__ __forceinline__ v2f vtanh(v2f a) {
    v2f r; r.x = fast_tanh(a.x); r.y = fast_tanh(a.y); return r;
}

__device__ __forceinline__ void load16(const float* __restrict__ X, size_t r, float (&x)[16]) {
    const float4* p4 = reinterpret_cast<const float4*>(X) + r * 4;
    float4 a = p4[0], b = p4[1], c = p4[2], d = p4[3];
    x[0]=a.x; x[1]=a.y; x[2]=a.z; x[3]=a.w;
    x[4]=b.x; x[5]=b.y; x[6]=b.z; x[7]=b.w;
    x[8]=c.x; x[9]=c.y; x[10]=c.z; x[11]=c.w;
    x[12]=d.x; x[13]=d.y; x[14]=d.z; x[15]=d.w;
}

__device__ __forceinline__ void load16_v2(const float* __restrict__ X, size_t rA, size_t rB,
                                          v2f (&x)[16]) {
    float a[16], b[16];
    load16(X, rA, a);
    load16(X, rB, b);
#pragma unroll
    for (int k = 0; k < 16; ++k) { x[k].x = a[k]; x[k].y = b[k]; }
}

__device__ __forceinline__ void store16_lane(float* __restrict__ X, size_t r,
                                             const v2f (&x)[16], int lane) {
    float4* p4 = reinterpret_cast<float4*>(X) + r * 4;
    if (lane == 0) {
        p4[0] = make_float4(x[0].x, x[1].x, x[2].x, x[3].x);
        p4[1] = make_float4(x[4].x, x[5].x, x[6].x, x[7].x);
        p4[2] = make_float4(x[8].x, x[9].x, x[10].x, x[11].x);
        p4[3] = make_float4(x[12].x, x[13].x, x[14].x, x[15].x);
    } else {
        p4[0] = make_float4(x[0].y, x[1].y, x[2].y, x[3].y);
        p4[1] = make_float4(x[4].y, x[5].y, x[6].y, x[7].y);
        p4[2] = make_float4(x[8].y, x[9].y, x[10].y, x[11].y);
        p4[3] = make_float4(x[12].y, x[13].y, x[14].y, x[15].y);
    }
}

__device__ __forceinline__ void emb16_v2(const v2f (&x)[16],
                                         const float* __restrict__ W1, const float* __restrict__ b1,
                                         const float* __restrict__ W2, const float* __restrict__ b2,
                                         v2f (&e)[16]) {
    v2f h[16];
#pragma unroll
    for (int i = 0; i < 16; ++i) {
        v2f a = vbc(b1[i]);
#pragma unroll
        for (int k = 0; k < 16; ++k) a = vfma(W1[i * 16 + k], x[k], a);
        h[i] = vtanh(a);
    }
#pragma unroll
    for (int i = 0; i < 16; ++i) {
        v2f a = vbc(b2[i]);
#pragma unroll
        for (int k = 0; k < 16; ++k) a = vfma(W2[i * 16 + k], h[k], a);
        e[i] = vtanh(a);
    }
}

__device__ __forceinline__ v2f att_logit_v2(const v2f (&e)[16], const float (&qk)[16],
                                            const float* __restrict__ Wr,
                                            const float* __restrict__ V) {
    v2f acc = vbc(0.0f);
#pragma unroll
    for (int i = 0; i < 16; ++i) {
        v2f r = vbc(qk[i]);
#pragma unroll
        for (int k = 0; k < 16; ++k) r = vfma(Wr[i * 16 + k], e[k], r);
        acc = vfma2(vbc(V[i]), vtanh(r), acc);
    }
    return acc;
}

__device__ __forceinline__ float wave_reduce_sum(float v) {
#pragma unroll
    for (int off = 32; off > 0; off >>= 1) v += __shfl_xor(v, off, 64);
    return v;
}

__device__ __forceinline__ void wave_reduce_argmax(float &v, int &idx) {
#pragma unroll
    for (int off = 32; off > 0; off >>= 1) {
        float ov = __shfl_xor(v, off, 64);
        int oi = __shfl_xor(idx, off, 64);
        if (ov > v || (ov == v && oi < idx)) { v = ov; idx = oi; }
    }
}

__device__ __forceinline__ float block_sum(float v) {
    __shared__ float sm[4];
    v = wave_reduce_sum(v);
    __syncthreads();
    if ((threadIdx.x & 63) == 0) sm[threadIdx.x >> 6] = v;
    __syncthreads();
    float r = sm[0] + sm[1] + sm[2] + sm[3];
    __syncthreads();
    return r;
}

__device__ __forceinline__ void block_argmax(float &v, int &i) {
    __shared__ float sv[4];
    __shared__ int si[4];
    wave_reduce_argmax(v, i);
    __syncthreads();
    if ((threadIdx.x & 63) == 0) { sv[threadIdx.x >> 6] = v; si[threadIdx.x >> 6] = i; }
    __syncthreads();
    float bv = sv[0]; int bi = si[0];
#pragma unroll
    for (int k = 1; k < 4; ++k)
        if (sv[k] > bv || (sv[k] == bv && si[k] < bi)) { bv = sv[k]; bi = si[k]; }
    v = bv; i = bi;
    __syncthreads();
}

__device__ __forceinline__ void block_sum17(float l, float (&s)[16], float* dst) {
    l = wave_reduce_sum(l);
#pragma unroll
    for (int i = 0; i < 16; ++i) s[i] = wave_reduce_sum(s[i]);
    __shared__ float red[4][17];
    int w = threadIdx.x >> 6, ln = threadIdx.x & 63;
    if (ln == 0) {
        red[w][0] = l;
#pragma unroll
        for (int i = 0; i < 16; ++i) red[w][1 + i] = s[i];
    }
    __syncthreads();
    if (threadIdx.x < 17)
        dst[threadIdx.x] = red[0][threadIdx.x] + red[1][threadIdx.x] + red[2][threadIdx.x] + red[3][threadIdx.x];
    __syncthreads();
}

__device__ __forceinline__ void block_argmax_sum_store(float best, int bi, float l,
                                                       float* S, int bid) {
    l = wave_reduce_sum(l);
    wave_reduce_argmax(best, bi);
    __shared__ float rl[4], rv[4];
    __shared__ int ri[4];
    int w = threadIdx.x >> 6, ln = threadIdx.x & 63;
    if (ln == 0) { rl[w] = l; rv[w] = best; ri[w] = bi; }
    __syncthreads();
    if (threadIdx.x == 0) {
        float L = rl[0] + rl[1] + rl[2] + rl[3];
        float v = rv[0]; int i = ri[0];
#pragma unroll
        for (int k = 1; k < 4; ++k)
            if (rv[k] > v || (rv[k] == v && ri[k] < i)) { v = rv[k]; i = ri[k]; }
        S[P2V + bid] = v;
        S[P2I + bid] = (float)i;   // exact: i < 2^24
        S[P2L + bid] = L;
    }
    __syncthreads();
}

// ---------------------------------------------------------------------------
// phase bodies (shared by fused-coop kernel and fallback kernels)
// ---------------------------------------------------------------------------

// P1: embeddings (+cache) + glimpse-1 partials. Role split by bid.
template <bool CACHE>
__device__ __forceinline__ void phase1(const Params& p, int bid) {
    const bool isJob = bid < p.nbj;
    const float* X  = isJob ? p.jobs : p.machines;
    const float* W1 = isJob ? p.jW1 : p.mW1;
    const float* b1 = isJob ? p.jb1 : p.mb1;
    const float* W2 = isJob ? p.jW2 : p.mW2;
    const float* b2 = isJob ? p.jb2 : p.mb2;
    const float* Wg = isJob ? p.aj_Wr : p.am_Wr;
    const float* Vg = isJob ? p.aj_V  : p.am_V;
    float* E = isJob ? p.Ej : p.Em;
    const int n  = isJob ? NJ : NM;
    const int nb = isJob ? p.nbj : p.nbm;
    const int b0 = isJob ? bid : bid - p.nbj;
    const int tid = (int)threadIdx.x;

    __shared__ float qk1s[16];
    if (tid < 16) {
        const float* Wq = isJob ? p.aj_Wq : p.am_Wq;
        const float* bq = isJob ? p.aj_bq : p.am_bq;
        float a = bq[tid];
#pragma unroll
        for (int k = 0; k < 16; ++k) a = fmaf(Wq[tid * 16 + k], p.last_j[k], a);
        qk1s[tid] = a;
    }
    __syncthreads();
    float qk[16];
#pragma unroll
    for (int i = 0; i < 16; ++i) qk[i] = qk1s[i];
    __syncthreads();

    const int half = nb * BLK, step = 2 * half;
    float l = 0.0f;
    v2f sa[16];
#pragma unroll
    for (int i = 0; i < 16; ++i) sa[i] = vbc(0.0f);

    for (int rA = b0 * BLK + tid; rA < n; rA += step) {
        const int rB = rA + half;
        const bool v1 = rB < n;
        const size_t aA = (size_t)rA, aB = (size_t)(v1 ? rB : rA);
        v2f x[16], e[16];
        load16_v2(X, aA, aB, x);
        emb16_v2(x, W1, b1, W2, b2, e);
        if (CACHE) {
            store16_lane(E, aA, e, 0);
            if (v1) store16_lane(E, aB, e, 1);
        }
        v2f lg = att_logit_v2(e, qk, Wg, Vg);
        // |logit| <= sum|V| ~ 0.6 -> no max-shift needed.
        v2f pw; pw.x = __expf(lg.x); pw.y = v1 ? __expf(lg.y) : 0.0f;
        l += pw.x + pw.y;
#pragma unroll
        for (int i = 0; i < 16; ++i) sa[i] = vfma2(pw, e[i], sa[i]);
    }
    float s[16];
#pragma unroll
    for (int i = 0; i < 16; ++i) s[i] = sa[i].x + sa[i].y;
    block_sum17(l, s, p.S + (isJob ? P1J : P1M) + (size_t)b0 * 17);
}

// P3: job pointer logits -> masked argmax + sum-exp partials. Whole grid.
template <bool CACHE>
__device__ __forceinline__ void phase3(const Params& p, int bid) {
    const int tid = (int)threadIdx.x;
    float qk[16];
#pragma unroll
    for (int i = 0; i < 16; ++i) qk[i] = p.S[S_QKJA + i];
    const int nbt = p.nbj + p.nbm;
    const int half = nbt * BLK, step = 2 * half;
    float best = -3.4e38f; int bi = 0x7fffffff; float l = 0.0f;
    for (int rA = bid * BLK + tid; rA < NJ; rA += step) {
        const int rB = rA + half;
        const bool v1 = rB < NJ;
        const size_t aA = (size_t)rA, aB = (size_t)(v1 ? rB : rA);
        v2f e[16];
        if (CACHE) {
            load16_v2(p.Ej, aA, aB, e);
        } else {
            v2f x[16];
            load16_v2(p.jobs, aA, aB, x);
            emb16_v2(x, p.jW1, p.jb1, p.jW2, p.jb2, e);
        }
        v2f lg = att_logit_v2(e, qk, p.ja_Wr, p.ja_V);
        const bool m0 = p.mask[aA] != 0;
        const bool m1 = v1 && (p.mask[aB] != 0);
        l += (m0 ? __expf(lg.x) : 0.0f) + (m1 ? __expf(lg.y) : 0.0f);
        float am0 = m0 ? lg.x : NEGV - 1.0f;
        float am1 = m1 ? lg.y : NEGV - 1.0f;
        // strict > with increasing index order => smallest index wins ties
        if (am0 > best) { best = am0; bi = rA; }
        if (am1 > best) { best = am1; bi = rB; }
    }
    block_argmax_sum_store(best, bi, l, p.S, bid);
}

// P5: glimpse-2 (role split, query e_js). Writes into P1 buffers.
template <bool CACHE>
__device__ __forceinline__ void phase5(const Params& p, int bid) {
    const bool isJob = bid < p.nbj;
    const float* X  = isJob ? p.jobs : p.machines;
    const float* W1 = isJob ? p.jW1 : p.mW1;
    const float* b1 = isJob ? p.jb1 : p.mb1;
    const float* W2 = isJob ? p.jW2 : p.mW2;
    const float* b2 = isJob ? p.jb2 : p.mb2;
    const float* Wg = isJob ? p.aj_Wr : p.am_Wr;
    const float* Vg = isJob ? p.aj_V  : p.am_V;
    const float* E  = isJob ? p.Ej : p.Em;
    const int n  = isJob ? NJ : NM;
    const int nb = isJob ? p.nbj : p.nbm;
    const int b0 = isJob ? bid : bid - p.nbj;
    const int tid = (int)threadIdx.x;

    float qk[16];
    {
        const float* src = p.S + (isJob ? S_QK2J : S_QK2M);
#pragma unroll
        for (int i = 0; i < 16; ++i) qk[i] = src[i];
    }
    const int half = nb * BLK, step = 2 * half;
    float l = 0.0f;
    v2f sa[16];
#pragma unroll
    for (int i = 0; i < 16; ++i) sa[i] = vbc(0.0f);

    for (int rA = b0 * BLK + tid; rA < n; rA += step) {
        const int rB = rA + half;
        const bool v1 = rB < n;
        const size_t aA = (size_t)rA, aB = (size_t)(v1 ? rB : rA);
        v2f e[16];
        if (CACHE) {
            load16_v2(E, aA, aB, e);
        } else {
            v2f x[16];
            load16_v2(X, aA, aB, x);
            emb16_v2(x, W1, b1, W2, b2, e);
        }
        v2f lg = att_logit_v2(e, qk, Wg, Vg);
        v2f pw; pw.x = __expf(lg.x); pw.y = v1 ? __expf(lg.y) : 0.0f;
        l += pw.x + pw.y;
#pragma unroll
        for (int i = 0; i < 16; ++i) sa[i] = vfma2(pw, e[i], sa[i]);
    }
    float s[16];
#pragma unroll
    for (int i = 0; i < 16; ++i) s[i] = sa[i].x + sa[i].y;
    block_sum17(l, s, p.S + (isJob ? P1J : P1M) + (size_t)b0 * 17);
}

// P7: machine logits -> argmax + sum-exp partials. Whole grid.
template <bool CACHE>
__device__ __forceinline__ void phase7(const Params& p, int bid) {
    const int tid = (int)threadIdx.x;
    float qk[16];
#pragma unroll
    for (int i = 0; i < 16; ++i) qk[i] = p.S[S_QKMA + i];
    const int nbt = p.nbj + p.nbm;
    const int half = nbt * BLK, step = 2 * half;
    float best = -3.4e38f; int bi = 0x7fffffff; float l = 0.0f;
    for (int rA = bid * BLK + tid; rA < NM; rA += step) {
        const int rB = rA + half;
        const bool v1 = rB < NM;
        const size_t aA = (size_t)rA, aB = (size_t)(v1 ? rB : rA);
        v2f e[16];
        if (CACHE) {
            load16_v2(p.Em, aA, aB, e);
        } else {
            v2f x[16];
            load16_v2(p.machines, aA, aB, x);
            emb16_v2(x, p.mW1, p.mb1, p.mW2, p.mb2, e);
        }
        v2f lg = att_logit_v2(e, qk, p.ma_Wr, p.ma_V);
        l += __expf(lg.x) + (v1 ? __expf(lg.y) : 0.0f);
        float am1 = v1 ? lg.y : -3.4e38f;
        if (lg.x > best) { best = lg.x; bi = rA; }
        if (am1 > best) { best = am1; bi = rB; }
    }
    block_argmax_sum_store(best, bi, l, p.S, bid);
}

// combine: partials -> g (g1|g2) -> next-stage qk. Single block.
__device__ void combine_g_device(const Params& p, int phase) {
    const float* PJ = p.S + P1J;
    const float* PM = p.S + P1M;
    float accJ[17], accM[17];
#pragma unroll
    for (int c = 0; c < 17; ++c) { accJ[c] = 0.0f; accM[c] = 0.0f; }
    for (int i = threadIdx.x; i < p.nbj; i += BLK)
#pragma unroll
        for (int c = 0; c < 17; ++c) accJ[c] += PJ[i * 17 + c];
    for (int i = threadIdx.x; i < p.nbm; i += BLK)
#pragma unroll
        for (int c = 0; c < 17; ++c) accM[c] += PM[i * 17 + c];

    __shared__ float totJ[17], totM[17];
    for (int c = 0; c < 17; ++c) {
        float t = block_sum(accJ[c]);
        if (threadIdx.x == 0) totJ[c] = t;
        t = block_sum(accM[c]);
        if (threadIdx.x == 0) totM[c] = t;
    }
    __syncthreads();

    __shared__ float cb[48], gbuf[16];
    if (threadIdx.x < 16) {
        int i = threadIdx.x;
        cb[i]      = phase ? p.S[S_EJS + i] : p.last_j[i];
        cb[16 + i] = totJ[1 + i] / totJ[0];
        cb[32 + i] = totM[1 + i] / totM[0];
    }
    __syncthreads();
    const float* gW  = phase ? p.g2W : p.g1W;
    const float* gbv = phase ? p.g2b : p.g1b;
    if (threadIdx.x < 16) {
        int i = threadIdx.x;
        float a = gbv[i];
#pragma unroll
        for (int k = 0; k < 48; ++k) a = fmaf(gW[i * 48 + k], cb[k], a);
        gbuf[i] = fast_tanh(a);
    }
    __syncthreads();
    const float* Wq = phase ? p.ma_Wq : p.ja_Wq;
    const float* bq = phase ? p.ma_bq : p.ja_bq;
    const int off = phase ? S_QKMA : S_QKJA;
    if (threadIdx.x < 16) {
        int i = threadIdx.x;
        float a = bq[i];
#pragma unroll
        for (int k = 0; k < 16; ++k) a = fmaf(Wq[i * 16 + k], gbuf[k], a);
        p.S[off + i] = a;
    }
    __syncthreads();
}

// combine2: global job argmax, logp_j, e_js, qk2j/qk2m. Single block.
__device__ void combine2_device(const Params& p) {
    const int nbt = p.nbj + p.nbm;
    float v = -3.4e38f; int vi = 0x7fffffff; float l = 0.0f;
    for (int i = threadIdx.x; i < nbt; i += BLK) {
        float pv = p.S[P2V + i];
        int pi = (int)p.S[P2I + i];
        if (pv > v || (pv == v && pi < vi)) { v = pv; vi = pi; }
        l += p.S[P2L + i];
    }
    l = block_sum(l);
    block_argmax(v, vi);
    const int sel = vi;

    __shared__ float xb[16], hb[16], eb[16];
    if (threadIdx.x < 16) xb[threadIdx.x] = p.jobs[(size_t)sel * 16 + threadIdx.x];
    __syncthreads();
    if (threadIdx.x < 16) {
        int i = threadIdx.x;
        float a = p.jb1[i];
#pragma unroll
        for (int k = 0; k < 16; ++k) a = fmaf(p.jW1[i * 16 + k], xb[k], a);
        hb[i] = fast_tanh(a);
    }
    __syncthreads();
    if (threadIdx.x < 16) {
        int i = threadIdx.x;
        float a = p.jb2[i];
#pragma unroll
        for (int k = 0; k < 16; ++k) a = fmaf(p.jW2[i * 16 + k], hb[k], a);
        float e = fast_tanh(a);
        eb[i] = e;
        p.S[S_EJS + i] = e;
    }
    __syncthreads();
    if (threadIdx.x < 16) {
        int i = threadIdx.x;
        float a1 = p.aj_bq[i], a2 = p.am_bq[i];
#pragma unroll
        for (int k = 0; k < 16; ++k) {
            a1 = fmaf(p.aj_Wq[i * 16 + k], eb[k], a1);
            a2 = fmaf(p.am_Wq[i * 16 + k], eb[k], a2);
        }
        p.S[S_QK2J + i] = a1;
        p.S[S_QK2M + i] = a2;
    }
    if (threadIdx.x == 0) {
        p.S[S_LOGPJ] = v - logf(l);
        p.S[S_SELJ] = (float)sel;
    }
    __syncthreads();
}

// final: machine argmax -> out
__device__ void final_device(const Params& p) {
    const int nbt = p.nbj + p.nbm;
    float v = -3.4e38f; int vi = 0x7fffffff; float l = 0.0f;
    for (int i = threadIdx.x; i < nbt; i += BLK) {
        float pv = p.S[P2V + i];
        int pi = (int)p.S[P2I + i];
        if (pv > v || (pv == v && pi < vi)) { v = pv; vi = pi; }
        l += p.S[P2L + i];
    }
    l = block_sum(l);
    block_argmax(v, vi);
    if (threadIdx.x == 0) {
        p.out[0] = p.S[S_SELJ];
        p.out[1] = (float)vi;
        p.out[2] = p.S[S_LOGPJ] + (v - logf(l));
    }
}

// ---------------------------------------------------------------------------
// fused cooperative kernel
// ---------------------------------------------------------------------------
template <bool CACHE>
__global__ __launch_bounds__(BLK, 3) void k_fused(Params p) {
    cg::grid_group grid = cg::this_grid();
    const int bid = (int)blockIdx.x;

    phase1<CACHE>(p, bid);
    __threadfence();
    grid.sync();

    if (bid == 0) combine_g_device(p, 0);
    __threadfence();
    grid.sync();

    phase3<CACHE>(p, bid);
    __threadfence();
    grid.sync();

    if (bid == 0) combine2_device(p);
    __threadfence();
    grid.sync();

    phase5<CACHE>(p, bid);
    __threadfence();
    grid.sync();

    if (bid == 0) combine_g_device(p, 1);
    __threadfence();
    grid.sync();

    phase7<CACHE>(p, bid);
    __threadfence();
    grid.sync();

    if (bid == 0) final_device(p);
}

// ---------------------------------------------------------------------------
// fallback multi-kernel wrappers (same phase bodies -> identical numerics)
// ---------------------------------------------------------------------------
template <bool CACHE>
__global__ __launch_bounds__(BLK) void k_p1(Params p) { phase1<CACHE>(p, (int)blockIdx.x); }
__global__ __launch_bounds__(BLK) void k_cg(Params p, int phase) { combine_g_device(p, phase); }
template <bool CACHE>
__global__ __launch_bounds__(BLK) void k_p3(Params p) { phase3<CACHE>(p, (int)blockIdx.x); }
__global__ __launch_bounds__(BLK) void k_c2(Params p) { combine2_device(p); }
template <bool CACHE>
__global__ __launch_bounds__(BLK) void k_p5(Params p) { phase5<CACHE>(p, (int)blockIdx.x); }
template <bool CACHE>
__global__ __launch_bounds__(BLK) void k_p7(Params p) { phase7<CACHE>(p, (int)blockIdx.x); }
__global__ __launch_bounds__(BLK) void k_c4(Params p) { final_device(p); }

// ---------------------------------------------------------------------------
template <bool CACHE>
static void launch_path(Params p, hipStream_t stream) {
    // --- try cooperative fusion, sized from the occupancy query -----------
    int dev = 0;
    (void)hipGetDevice(&dev);
    int numCU = 0;
    (void)hipDeviceGetAttribute(&numCU, hipDeviceAttributeMultiprocessorCount, dev);
    int maxPerCU = 0;
    hipError_t qe = hipOccupancyMaxActiveBlocksPerMultiprocessor(
        &maxPerCU, reinterpret_cast<const void*>(&k_fused<CACHE>), BLK, 0);

    if (qe == hipSuccess && maxPerCU > 0 && numCU > 0) {
        int perCU = maxPerCU < 4 ? maxPerCU : 4;   // cap grid <= 4*numCU (<=1024)
        int nbt = perCU * numCU;
        if (nbt > NBT_MAX) nbt = NBT_MAX;
        if (nbt >= 192) {   // enough parallelism to bother
            p.nbj = (2 * nbt) / 3;
            p.nbm = nbt - p.nbj;
            void* args[] = { (void*)&p };
            hipError_t le = hipLaunchCooperativeKernel(
                reinterpret_cast<const void*>(&k_fused<CACHE>),
                dim3(nbt), dim3(BLK), args, 0, stream);
            if (le == hipSuccess) return;
        }
    }

    // --- fallback: 8 dispatches, R3-scale grids ---------------------------
    p.nbj = NBJ_MAX;   // 2048
    p.nbm = NBM_MAX;   // 1024
    const int nbt = p.nbj + p.nbm;
    k_p1<CACHE><<<nbt, BLK, 0, stream>>>(p);
    k_cg<<<1, BLK, 0, stream>>>(p, 0);
    k_p3<CACHE><<<nbt, BLK, 0, stream>>>(p);
    k_c2<<<1, BLK, 0, stream>>>(p);
    k_p5<CACHE><<<nbt, BLK, 0, stream>>>(p);
    k_cg<<<1, BLK, 0, stream>>>(p, 1);
    k_p7<CACHE><<<nbt, BLK, 0, stream>>>(p);
    k_c4<<<1, BLK, 0, stream>>>(p);
}

extern "C" void kernel_launch(void* const* d_in, const int* in_sizes, int n_in,
                              void* d_out, int out_size, void* d_ws, size_t ws_size,
                              hipStream_t stream) {
    Params p;
    p.jobs     = (const float*)d_in[0];
    p.machines = (const float*)d_in[1];
    p.mask     = (const int*)d_in[2];
    p.jW1 = (const float*)d_in[3];  p.jb1 = (const float*)d_in[4];
    p.jW2 = (const float*)d_in[5];  p.jb2 = (const float*)d_in[6];
    p.mW1 = (const float*)d_in[7];  p.mb1 = (const float*)d_in[8];
    p.mW2 = (const float*)d_in[9];  p.mb2 = (const float*)d_in[10];
    p.aj_Wq = (const float*)d_in[11]; p.aj_bq = (const float*)d_in[12];
    p.aj_Wr = (const float*)d_in[13]; p.aj_V  = (const float*)d_in[14];
    p.am_Wq = (const float*)d_in[15]; p.am_bq = (const float*)d_in[16];
    p.am_Wr = (const float*)d_in[17]; p.am_V  = (const float*)d_in[18];
    p.ja_Wq = (const float*)d_in[19]; p.ja_bq = (const float*)d_in[20];
    p.ja_Wr = (const float*)d_in[21]; p.ja_V  = (const float*)d_in[22];
    p.ma_Wq = (const float*)d_in[23]; p.ma_bq = (const float*)d_in[24];
    p.ma_Wr = (const float*)d_in[25]; p.ma_V  = (const float*)d_in[26];
    p.g1W = (const float*)d_in[27]; p.g1b = (const float*)d_in[28];
    p.g2W = (const float*)d_in[29]; p.g2b = (const float*)d_in[30];
    p.last_j = (const float*)d_in[31];
    p.S = (float*)d_ws;
    p.Ej = (float*)d_ws + E_OFF;
    p.Em = p.Ej + (size_t)NJ * 16;
    p.out = (float*)d_out;
    p.nbj = 0; p.nbm = 0;

    const size_t needed = (E_OFF + (size_t)(NJ + NM) * 16) * sizeof(float);
    const bool cache = ws_size >= needed;

    if (cache) launch_path<true>(p, stream);
    else       launch_path<false>(p, stream);
}

// Round 7
// 461.118 us; speedup vs baseline: 4.3491x; 4.3491x over previous
//
#include <hip/hip_runtime.h>
#include <cstddef>
#include <cstdint>

// ---------------------------------------------------------------------------
// attention_net_noc: pointer-network decode step.
// R7: multi-kernel again (R6 proved grid.sync costs ~350us/sync at 1000
// blocks on 8-XCD MI355X -> fusion dead). Two changes vs R3:
//  (1) last-block-done combines: each big kernel's final-arriving block runs
//      the global combine inline (threadfence + atomicAdd arrive counter) ->
//      8 dispatches become 4 (+1 16-byte memset for counters).
//  (2) 4 rows/thread (two interleaved v2f pairs): each wave-uniform weight
//      load feeds 4 FMAs -> higher VALU duty (R3 was 62% with 2 rows).
// fp32 throughout; argmax tie-break = smallest index (matches jnp.argmax).
// ---------------------------------------------------------------------------

constexpr int NJ = 1000000;
constexpr int NM = 500000;
constexpr float NEGV = -1e8f;

constexpr int BLK = 256;
constexpr int RPB = 1024;                   // rows per block = 4 per thread
constexpr int GJ = (NJ + RPB - 1) / RPB;    // 977
constexpr int GM = (NM + RPB - 1) / RPB;    // 489
constexpr int G1 = GJ + GM;                 // 1466

// ---- workspace layout (float offsets from start of d_ws) ----
constexpr int S_QKJA = 0;    // 16: ja_Wq@g1 + ja_bq
constexpr int S_QK2J = 16;   // 16: aj_Wq@e_js + aj_bq
constexpr int S_QK2M = 32;   // 16: am_Wq@e_js + am_bq
constexpr int S_EJS  = 48;   // 16: E_j[sel_j]
constexpr int S_QKMA = 64;   // 16: ma_Wq@g2 + ma_bq
constexpr int S_LOGPJ = 80;
constexpr int S_SELJ  = 81;  // stored as float (exact, < 2^24)
constexpr int S_CNT   = 88;  // 4 ints: arrive counters (zeroed by memset)
constexpr int P1J = 96;                    // GJ*17 glimpse partials (l,s[16])
constexpr int P1M = P1J + GJ * 17;         // GM*17
constexpr int P2V = P1M + GM * 17;         // GJ argmax vals (P7 reuses, GM<GJ)
constexpr int P2I = P2V + GJ;
constexpr int P2L = P2I + GJ;
constexpr size_t E_OFF = 65536;            // float offset of E_j cache
static_assert(P2L + GJ <= (int)E_OFF, "partials overflow into E cache");

typedef float v2f __attribute__((ext_vector_type(2)));

struct Params {
    const float *jobs, *machines;
    const int *mask;
    const float *jW1, *jb1, *jW2, *jb2;
    const float *mW1, *mb1, *mW2, *mb2;
    const float *aj_Wq, *aj_bq, *aj_Wr, *aj_V;
    const float *am_Wq, *am_bq, *am_Wr, *am_V;
    const float *ja_Wq, *ja_bq, *ja_Wr, *ja_V;
    const float *ma_Wq, *ma_bq, *ma_Wr, *ma_V;
    const float *g1W, *g1b, *g2W, *g2b, *last_j;
    float *S;        // smalls + partials (in ws)
    int   *cnt;      // 4 arrive counters (in ws, memset to 0 each launch)
    float *Ej, *Em;  // embedding cache (in ws; used only if CACHE)
    float *out;
};

// ---------------------------------------------------------------------------
// device helpers (fp32 numerics identical to R3)
// ---------------------------------------------------------------------------

__device__ __forceinline__ float fast_tanh(float x) {
    float e = __expf(2.0f * x);
    return 1.0f - __fdividef(2.0f, e + 1.0f);
}

__device__ __forceinline__ v2f vbc(float a) { v2f r; r.x = a; r.y = a; return r; }

// packed fma: one v_pk_fma_f32 issue slot for two fp32 FMAs (bit-identical)
__device__ __forceinline__ v2f vfma(float w, v2f b, v2f c) {
    return __builtin_elementwise_fma(vbc(w), b, c);
}
__device__ __forceinline__ v2f vfma2(v2f a, v2f b, v2f c) {
    return __builtin_elementwise_fma(a, b, c);
}
__device__ __forceinline__ v2f vtanh(v2f a) {
    v2f r; r.x = fast_tanh(a.x); r.y = fast_tanh(a.y); return r;
}

__device__ __forceinline__ void load16(const float* __restrict__ X, size_t r, float (&x)[16]) {
    const float4* p4 = reinterpret_cast<const float4*>(X) + r * 4;
    float4 a = p4[0], b = p4[1], c = p4[2], d = p4[3];
    x[0]=a.x; x[1]=a.y; x[2]=a.z; x[3]=a.w;
    x[4]=b.x; x[5]=b.y; x[6]=b.z; x[7]=b.w;
    x[8]=c.x; x[9]=c.y; x[10]=c.z; x[11]=c.w;
    x[12]=d.x; x[13]=d.y; x[14]=d.z; x[15]=d.w;
}

// load rows rA,rB packed feature-wise into v2f lanes (.x=rowA, .y=rowB)
__device__ __forceinline__ void load16_v2(const float* __restrict__ X, size_t rA, size_t rB,
                                          v2f (&x)[16]) {
    float a[16], b[16];
    load16(X, rA, a);
    load16(X, rB, b);
#pragma unroll
    for (int k = 0; k < 16; ++k) { x[k].x = a[k]; x[k].y = b[k]; }
}

__device__ __forceinline__ void store16_lane(float* __restrict__ X, size_t r,
                                             const v2f (&x)[16], int lane) {
    float4* p4 = reinterpret_cast<float4*>(X) + r * 4;
    if (lane == 0) {
        p4[0] = make_float4(x[0].x, x[1].x, x[2].x, x[3].x);
        p4[1] = make_float4(x[4].x, x[5].x, x[6].x, x[7].x);
        p4[2] = make_float4(x[8].x, x[9].x, x[10].x, x[11].x);
        p4[3] = make_float4(x[12].x, x[13].x, x[14].x, x[15].x);
    } else {
        p4[0] = make_float4(x[0].y, x[1].y, x[2].y, x[3].y);
        p4[1] = make_float4(x[4].y, x[5].y, x[6].y, x[7].y);
        p4[2] = make_float4(x[8].y, x[9].y, x[10].y, x[11].y);
        p4[3] = make_float4(x[12].y, x[13].y, x[14].y, x[15].y);
    }
}

// 4-row MLP: two v2f pairs interleaved, every weight load feeds 4 FMAs.
__device__ __forceinline__ void emb16_v4(const v2f (&x1)[16], const v2f (&x2)[16],
                                         const float* __restrict__ W1, const float* __restrict__ b1,
                                         const float* __restrict__ W2, const float* __restrict__ b2,
                                         v2f (&e1)[16], v2f (&e2)[16]) {
    v2f h1[16], h2[16];
#pragma unroll
    for (int i = 0; i < 16; ++i) {
        v2f a1 = vbc(b1[i]), a2 = a1;
#pragma unroll
        for (int k = 0; k < 16; ++k) {
            float w = W1[i * 16 + k];
            a1 = vfma(w, x1[k], a1);
            a2 = vfma(w, x2[k], a2);
        }
        h1[i] = vtanh(a1);
        h2[i] = vtanh(a2);
    }
#pragma unroll
    for (int i = 0; i < 16; ++i) {
        v2f a1 = vbc(b2[i]), a2 = a1;
#pragma unroll
        for (int k = 0; k < 16; ++k) {
            float w = W2[i * 16 + k];
            a1 = vfma(w, h1[k], a1);
            a2 = vfma(w, h2[k], a2);
        }
        e1[i] = vtanh(a1);
        e2[i] = vtanh(a2);
    }
}

__device__ __forceinline__ void att_logit_v4(const v2f (&e1)[16], const v2f (&e2)[16],
                                             const float (&qk)[16],
                                             const float* __restrict__ Wr,
                                             const float* __restrict__ V,
                                             v2f &o1, v2f &o2) {
    v2f a1 = vbc(0.0f), a2 = vbc(0.0f);
#pragma unroll
    for (int i = 0; i < 16; ++i) {
        v2f r1 = vbc(qk[i]), r2 = r1;
#pragma unroll
        for (int k = 0; k < 16; ++k) {
            float w = Wr[i * 16 + k];
            r1 = vfma(w, e1[k], r1);
            r2 = vfma(w, e2[k], r2);
        }
        v2f vv = vbc(V[i]);
        a1 = vfma2(vv, vtanh(r1), a1);
        a2 = vfma2(vv, vtanh(r2), a2);
    }
    o1 = a1;
    o2 = a2;
}

__device__ __forceinline__ float wave_reduce_sum(float v) {
#pragma unroll
    for (int off = 32; off > 0; off >>= 1) v += __shfl_xor(v, off, 64);
    return v;
}

__device__ __forceinline__ void wave_reduce_argmax(float &v, int &idx) {
#pragma unroll
    for (int off = 32; off > 0; off >>= 1) {
        float ov = __shfl_xor(v, off, 64);
        int oi = __shfl_xor(idx, off, 64);
        if (ov > v || (ov == v && oi < idx)) { v = ov; idx = oi; }
    }
}

__device__ __forceinline__ float block_sum(float v) {
    __shared__ float sm[4];
    v = wave_reduce_sum(v);
    __syncthreads();
    if ((threadIdx.x & 63) == 0) sm[threadIdx.x >> 6] = v;
    __syncthreads();
    float r = sm[0] + sm[1] + sm[2] + sm[3];
    __syncthreads();
    return r;
}

__device__ __forceinline__ void block_argmax(float &v, int &i) {
    __shared__ float sv[4];
    __shared__ int si[4];
    wave_reduce_argmax(v, i);
    __syncthreads();
    if ((threadIdx.x & 63) == 0) { sv[threadIdx.x >> 6] = v; si[threadIdx.x >> 6] = i; }
    __syncthreads();
    float bv = sv[0]; int bi = si[0];
#pragma unroll
    for (int k = 1; k < 4; ++k)
        if (sv[k] > bv || (sv[k] == bv && si[k] < bi)) { bv = sv[k]; bi = si[k]; }
    v = bv; i = bi;
    __syncthreads();
}

// reduce (l, s[16]) across the block, write 17 floats to dst; ends synced
__device__ __forceinline__ void block_sum17(float l, float (&s)[16], float* dst) {
    l = wave_reduce_sum(l);
#pragma unroll
    for (int i = 0; i < 16; ++i) s[i] = wave_reduce_sum(s[i]);
    __shared__ float red[4][17];
    int w = threadIdx.x >> 6, ln = threadIdx.x & 63;
    if (ln == 0) {
        red[w][0] = l;
#pragma unroll
        for (int i = 0; i < 16; ++i) red[w][1 + i] = s[i];
    }
    __syncthreads();
    if (threadIdx.x < 17)
        dst[threadIdx.x] = red[0][threadIdx.x] + red[1][threadIdx.x] + red[2][threadIdx.x] + red[3][threadIdx.x];
    __syncthreads();
}

__device__ __forceinline__ void block_argmax_sum_store(float best, int bi, float l,
                                                       float* S, int bid) {
    l = wave_reduce_sum(l);
    wave_reduce_argmax(best, bi);
    __shared__ float rl[4], rv[4];
    __shared__ int ri[4];
    int w = threadIdx.x >> 6, ln = threadIdx.x & 63;
    if (ln == 0) { rl[w] = l; rv[w] = best; ri[w] = bi; }
    __syncthreads();
    if (threadIdx.x == 0) {
        float L = rl[0] + rl[1] + rl[2] + rl[3];
        float v = rv[0]; int i = ri[0];
#pragma unroll
        for (int k = 1; k < 4; ++k)
            if (rv[k] > v || (rv[k] == v && ri[k] < i)) { v = rv[k]; i = ri[k]; }
        S[P2V + bid] = v;
        S[P2I + bid] = (float)i;   // exact: i < 2^24
        S[P2L + bid] = L;
    }
    __syncthreads();
}

// last-block-done arrive: returns true in ALL threads of the final block.
// Release: stores are in L2 by the barrier inside the preceding reduction;
// tid0's __threadfence (wbl2) makes them device-visible before the atomic.
__device__ __forceinline__ bool arrive_last(int* counter, int total) {
    __shared__ int lastFlag;
    if (threadIdx.x == 0) {
        __threadfence();
        int old = atomicAdd(counter, 1);
        lastFlag = (old == total - 1) ? 1 : 0;
    }
    __syncthreads();
    bool last = (lastFlag != 0);
    if (last) __threadfence();   // acquire before reading other blocks' data
    return last;
}

// ---------------------------------------------------------------------------
// combine bodies (run by the LAST block of the preceding phase)
// ---------------------------------------------------------------------------
__device__ void combine_g_device(const Params& p, int phase) {
    const float* PJ = p.S + P1J;
    const float* PM = p.S + P1M;
    float accJ[17], accM[17];
#pragma unroll
    for (int c = 0; c < 17; ++c) { accJ[c] = 0.0f; accM[c] = 0.0f; }
    for (int i = threadIdx.x; i < GJ; i += BLK)
#pragma unroll
        for (int c = 0; c < 17; ++c) accJ[c] += PJ[i * 17 + c];
    for (int i = threadIdx.x; i < GM; i += BLK)
#pragma unroll
        for (int c = 0; c < 17; ++c) accM[c] += PM[i * 17 + c];

    __shared__ float totJ[17], totM[17];
    for (int c = 0; c < 17; ++c) {
        float t = block_sum(accJ[c]);
        if (threadIdx.x == 0) totJ[c] = t;
        t = block_sum(accM[c]);
        if (threadIdx.x == 0) totM[c] = t;
    }
    __syncthreads();

    __shared__ float cb[48], gbuf[16];
    if (threadIdx.x < 16) {
        int i = threadIdx.x;
        cb[i]      = phase ? p.S[S_EJS + i] : p.last_j[i];
        cb[16 + i] = totJ[1 + i] / totJ[0];   // softmax-weighted sum / partition
        cb[32 + i] = totM[1 + i] / totM[0];
    }
    __syncthreads();
    const float* gW  = phase ? p.g2W : p.g1W;
    const float* gbv = phase ? p.g2b : p.g1b;
    if (threadIdx.x < 16) {
        int i = threadIdx.x;
        float a = gbv[i];
#pragma unroll
        for (int k = 0; k < 48; ++k) a = fmaf(gW[i * 48 + k], cb[k], a);
        gbuf[i] = fast_tanh(a);
    }
    __syncthreads();
    const float* Wq = phase ? p.ma_Wq : p.ja_Wq;
    const float* bq = phase ? p.ma_bq : p.ja_bq;
    const int off = phase ? S_QKMA : S_QKJA;
    if (threadIdx.x < 16) {
        int i = threadIdx.x;
        float a = bq[i];
#pragma unroll
        for (int k = 0; k < 16; ++k) a = fmaf(Wq[i * 16 + k], gbuf[k], a);
        p.S[off + i] = a;
    }
}

__device__ void combine2_device(const Params& p) {
    float v = -3.4e38f; int vi = 0x7fffffff; float l = 0.0f;
    for (int i = threadIdx.x; i < GJ; i += BLK) {
        float pv = p.S[P2V + i];
        int pi = (int)p.S[P2I + i];
        if (pv > v || (pv == v && pi < vi)) { v = pv; vi = pi; }
        l += p.S[P2L + i];
    }
    l = block_sum(l);
    block_argmax(v, vi);
    const int sel = vi;

    __shared__ float xb[16], hb[16], eb[16];
    if (threadIdx.x < 16) xb[threadIdx.x] = p.jobs[(size_t)sel * 16 + threadIdx.x];
    __syncthreads();
    if (threadIdx.x < 16) {
        int i = threadIdx.x;
        float a = p.jb1[i];
#pragma unroll
        for (int k = 0; k < 16; ++k) a = fmaf(p.jW1[i * 16 + k], xb[k], a);
        hb[i] = fast_tanh(a);
    }
    __syncthreads();
    if (threadIdx.x < 16) {
        int i = threadIdx.x;
        float a = p.jb2[i];
#pragma unroll
        for (int k = 0; k < 16; ++k) a = fmaf(p.jW2[i * 16 + k], hb[k], a);
        float e = fast_tanh(a);
        eb[i] = e;
        p.S[S_EJS + i] = e;
    }
    __syncthreads();
    if (threadIdx.x < 16) {
        int i = threadIdx.x;
        float a1 = p.aj_bq[i], a2 = p.am_bq[i];
#pragma unroll
        for (int k = 0; k < 16; ++k) {
            a1 = fmaf(p.aj_Wq[i * 16 + k], eb[k], a1);
            a2 = fmaf(p.am_Wq[i * 16 + k], eb[k], a2);
        }
        p.S[S_QK2J + i] = a1;
        p.S[S_QK2M + i] = a2;
    }
    if (threadIdx.x == 0) {
        p.S[S_LOGPJ] = v - logf(l);     // log_softmax at the argmax
        p.S[S_SELJ] = (float)sel;
    }
}

__device__ void final_device(const Params& p) {
    float v = -3.4e38f; int vi = 0x7fffffff; float l = 0.0f;
    for (int i = threadIdx.x; i < GM; i += BLK) {
        float pv = p.S[P2V + i];
        int pi = (int)p.S[P2I + i];
        if (pv > v || (pv == v && pi < vi)) { v = pv; vi = pi; }
        l += p.S[P2L + i];
    }
    l = block_sum(l);
    block_argmax(v, vi);
    if (threadIdx.x == 0) {
        p.out[0] = p.S[S_SELJ];
        p.out[1] = (float)vi;
        p.out[2] = p.S[S_LOGPJ] + (v - logf(l));
    }
}

// ---------------------------------------------------------------------------
// K1: embeddings (+cache) + glimpse-1 partials; last block -> g1 -> S_QKJA.
// blocks [0,GJ) jobs, [GJ,G1) machines. 4 rows/thread (rA,+256,+512,+768).
// ---------------------------------------------------------------------------
template <bool CACHE>
__global__ __launch_bounds__(BLK) void k_p1(Params p) {
    const int bid = (int)blockIdx.x;
    const int tid = (int)threadIdx.x;
    const bool isJob = bid < GJ;
    const float* X  = isJob ? p.jobs : p.machines;
    const float* W1 = isJob ? p.jW1 : p.mW1;
    const float* b1 = isJob ? p.jb1 : p.mb1;
    const float* W2 = isJob ? p.jW2 : p.mW2;
    const float* b2 = isJob ? p.jb2 : p.mb2;
    const float* Wg = isJob ? p.aj_Wr : p.am_Wr;
    const float* Vg = isJob ? p.aj_V  : p.am_V;
    float* E = isJob ? p.Ej : p.Em;
    const int n  = isJob ? NJ : NM;
    const int b0 = isJob ? bid : bid - GJ;

    __shared__ float qk1s[16];
    if (tid < 16) {
        const float* Wq = isJob ? p.aj_Wq : p.am_Wq;
        const float* bq = isJob ? p.aj_bq : p.am_bq;
        float a = bq[tid];
#pragma unroll
        for (int k = 0; k < 16; ++k) a = fmaf(Wq[tid * 16 + k], p.last_j[k], a);
        qk1s[tid] = a;
    }
    __syncthreads();
    float qk[16];
#pragma unroll
    for (int i = 0; i < 16; ++i) qk[i] = qk1s[i];
    __syncthreads();

    const int rA = b0 * RPB + tid;            // always < n by grid sizing
    const int rB = rA + BLK, rC = rA + 2 * BLK, rD = rA + 3 * BLK;
    const bool vB = rB < n, vC = rC < n, vD = rD < n;

    v2f x1[16], x2[16], e1[16], e2[16];
    load16_v2(X, (size_t)rA, (size_t)(vB ? rB : rA), x1);
    load16_v2(X, (size_t)(vC ? rC : rA), (size_t)(vD ? rD : rA), x2);
    emb16_v4(x1, x2, W1, b1, W2, b2, e1, e2);
    if (CACHE) {
        store16_lane(E, (size_t)rA, e1, 0);
        if (vB) store16_lane(E, (size_t)rB, e1, 1);
        if (vC) store16_lane(E, (size_t)rC, e2, 0);
        if (vD) store16_lane(E, (size_t)rD, e2, 1);
    }
    v2f lg1, lg2;
    att_logit_v4(e1, e2, qk, Wg, Vg, lg1, lg2);
    // |logit| <= sum|V| ~ 0.6 -> exp never overflows; no max-shift needed.
    v2f pw1, pw2;
    pw1.x = __expf(lg1.x);
    pw1.y = vB ? __expf(lg1.y) : 0.0f;
    pw2.x = vC ? __expf(lg2.x) : 0.0f;
    pw2.y = vD ? __expf(lg2.y) : 0.0f;
    float l = (pw1.x + pw1.y) + (pw2.x + pw2.y);
    float s[16];
#pragma unroll
    for (int i = 0; i < 16; ++i) {
        v2f t = pw1 * e1[i];
        t = vfma2(pw2, e2[i], t);
        s[i] = t.x + t.y;
    }
    block_sum17(l, s, p.S + (isJob ? P1J : P1M) + (size_t)b0 * 17);

    if (arrive_last(p.cnt + 0, G1)) combine_g_device(p, 0);
}

// ---------------------------------------------------------------------------
// K3: job pointer logits -> masked argmax + sum-exp; last block -> combine2.
// ---------------------------------------------------------------------------
template <bool CACHE>
__global__ __launch_bounds__(BLK) void k_p3(Params p) {
    const int bid = (int)blockIdx.x;
    const int tid = (int)threadIdx.x;
    float qk[16];
#pragma unroll
    for (int i = 0; i < 16; ++i) qk[i] = p.S[S_QKJA + i];

    const int rA = bid * RPB + tid;
    const int rB = rA + BLK, rC = rA + 2 * BLK, rD = rA + 3 * BLK;
    const bool vB = rB < NJ, vC = rC < NJ, vD = rD < NJ;
    const size_t aB = (size_t)(vB ? rB : rA);
    const size_t aC = (size_t)(vC ? rC : rA);
    const size_t aD = (size_t)(vD ? rD : rA);

    v2f e1[16], e2[16];
    if (CACHE) {
        load16_v2(p.Ej, (size_t)rA, aB, e1);
        load16_v2(p.Ej, aC, aD, e2);
    } else {
        v2f x1[16], x2[16];
        load16_v2(p.jobs, (size_t)rA, aB, x1);
        load16_v2(p.jobs, aC, aD, x2);
        emb16_v4(x1, x2, p.jW1, p.jb1, p.jW2, p.jb2, e1, e2);
    }
    v2f lg1, lg2;
    att_logit_v4(e1, e2, qk, p.ja_Wr, p.ja_V, lg1, lg2);
    const bool mA = p.mask[rA] != 0;
    const bool mB = vB && (p.mask[aB] != 0);
    const bool mC = vC && (p.mask[aC] != 0);
    const bool mD = vD && (p.mask[aD] != 0);
    float l = (mA ? __expf(lg1.x) : 0.0f) + (mB ? __expf(lg1.y) : 0.0f)
            + (mC ? __expf(lg2.x) : 0.0f) + (mD ? __expf(lg2.y) : 0.0f);
    // candidates in ascending index order, strict > => smallest index on ties
    float best = mA ? lg1.x : NEGV - 1.0f;
    int bi = rA;
    float c;
    c = mB ? lg1.y : NEGV - 1.0f; if (c > best) { best = c; bi = rB; }
    c = mC ? lg2.x : NEGV - 1.0f; if (c > best) { best = c; bi = rC; }
    c = mD ? lg2.y : NEGV - 1.0f; if (c > best) { best = c; bi = rD; }

    block_argmax_sum_store(best, bi, l, p.S, bid);

    if (arrive_last(p.cnt + 1, GJ)) combine2_device(p);
}

// ---------------------------------------------------------------------------
// K5: glimpse-2 (query e_js); last block -> g2 -> S_QKMA. P1-style role split.
// ---------------------------------------------------------------------------
template <bool CACHE>
__global__ __launch_bounds__(BLK) void k_p5(Params p) {
    const int bid = (int)blockIdx.x;
    const int tid = (int)threadIdx.x;
    const bool isJob = bid < GJ;
    const float* X  = isJob ? p.jobs : p.machines;
    const float* W1 = isJob ? p.jW1 : p.mW1;
    const float* b1 = isJob ? p.jb1 : p.mb1;
    const float* W2 = isJob ? p.jW2 : p.mW2;
    const float* b2 = isJob ? p.jb2 : p.mb2;
    const float* Wg = isJob ? p.aj_Wr : p.am_Wr;
    const float* Vg = isJob ? p.aj_V  : p.am_V;
    const float* E  = isJob ? p.Ej : p.Em;
    const int n  = isJob ? NJ : NM;
    const int b0 = isJob ? bid : bid - GJ;

    float qk[16];
    {
        const float* src = p.S + (isJob ? S_QK2J : S_QK2M);
#pragma unroll
        for (int i = 0; i < 16; ++i) qk[i] = src[i];
    }

    const int rA = b0 * RPB + tid;
    const int rB = rA + BLK, rC = rA + 2 * BLK, rD = rA + 3 * BLK;
    const bool vB = rB < n, vC = rC < n, vD = rD < n;
    const size_t aB = (size_t)(vB ? rB : rA);
    const size_t aC = (size_t)(vC ? rC : rA);
    const size_t aD = (size_t)(vD ? rD : rA);

    v2f e1[16], e2[16];
    if (CACHE) {
        load16_v2(E, (size_t)rA, aB, e1);
        load16_v2(E, aC, aD, e2);
    } else {
        v2f x1[16], x2[16];
        load16_v2(X, (size_t)rA, aB, x1);
        load16_v2(X, aC, aD, x2);
        emb16_v4(x1, x2, W1, b1, W2, b2, e1, e2);
    }
    v2f lg1, lg2;
    att_logit_v4(e1, e2, qk, Wg, Vg, lg1, lg2);
    v2f pw1, pw2;
    pw1.x = __expf(lg1.x);
    pw1.y = vB ? __expf(lg1.y) : 0.0f;
    pw2.x = vC ? __expf(lg2.x) : 0.0f;
    pw2.y = vD ? __expf(lg2.y) : 0.0f;
    float l = (pw1.x + pw1.y) + (pw2.x + pw2.y);
    float s[16];
#pragma unroll
    for (int i = 0; i < 16; ++i) {
        v2f t = pw1 * e1[i];
        t = vfma2(pw2, e2[i], t);
        s[i] = t.x + t.y;
    }
    block_sum17(l, s, p.S + (isJob ? P1J : P1M) + (size_t)b0 * 17);

    if (arrive_last(p.cnt + 2, G1)) combine_g_device(p, 1);
}

// ---------------------------------------------------------------------------
// K7: machine logits -> argmax + sum-exp; last block -> final output.
// ---------------------------------------------------------------------------
template <bool CACHE>
__global__ __launch_bounds__(BLK) void k_p7(Params p) {
    const int bid = (int)blockIdx.x;
    const int tid = (int)threadIdx.x;
    float qk[16];
#pragma unroll
    for (int i = 0; i < 16; ++i) qk[i] = p.S[S_QKMA + i];

    const int rA = bid * RPB + tid;
    const int rB = rA + BLK, rC = rA + 2 * BLK, rD = rA + 3 * BLK;
    const bool vB = rB < NM, vC = rC < NM, vD = rD < NM;
    const size_t aB = (size_t)(vB ? rB : rA);
    const size_t aC = (size_t)(vC ? rC : rA);
    const size_t aD = (size_t)(vD ? rD : rA);

    v2f e1[16], e2[16];
    if (CACHE) {
        load16_v2(p.Em, (size_t)rA, aB, e1);
        load16_v2(p.Em, aC, aD, e2);
    } else {
        v2f x1[16], x2[16];
        load16_v2(p.machines, (size_t)rA, aB, x1);
        load16_v2(p.machines, aC, aD, x2);
        emb16_v4(x1, x2, p.mW1, p.mb1, p.mW2, p.mb2, e1, e2);
    }
    v2f lg1, lg2;
    att_logit_v4(e1, e2, qk, p.ma_Wr, p.ma_V, lg1, lg2);
    float l = __expf(lg1.x) + (vB ? __expf(lg1.y) : 0.0f)
            + (vC ? __expf(lg2.x) : 0.0f) + (vD ? __expf(lg2.y) : 0.0f);
    float best = lg1.x;
    int bi = rA;
    float c;
    c = vB ? lg1.y : -3.4e38f; if (c > best) { best = c; bi = rB; }
    c = vC ? lg2.x : -3.4e38f; if (c > best) { best = c; bi = rC; }
    c = vD ? lg2.y : -3.4e38f; if (c > best) { best = c; bi = rD; }

    block_argmax_sum_store(best, bi, l, p.S, bid);

    if (arrive_last(p.cnt + 3, GM)) final_device(p);
}

// ---------------------------------------------------------------------------
extern "C" void kernel_launch(void* const* d_in, const int* in_sizes, int n_in,
                              void* d_out, int out_size, void* d_ws, size_t ws_size,
                              hipStream_t stream) {
    Params p;
    p.jobs     = (const float*)d_in[0];
    p.machines = (const float*)d_in[1];
    p.mask     = (const int*)d_in[2];
    p.jW1 = (const float*)d_in[3];  p.jb1 = (const float*)d_in[4];
    p.jW2 = (const float*)d_in[5];  p.jb2 = (const float*)d_in[6];
    p.mW1 = (const float*)d_in[7];  p.mb1 = (const float*)d_in[8];
    p.mW2 = (const float*)d_in[9];  p.mb2 = (const float*)d_in[10];
    p.aj_Wq = (const float*)d_in[11]; p.aj_bq = (const float*)d_in[12];
    p.aj_Wr = (const float*)d_in[13]; p.aj_V  = (const float*)d_in[14];
    p.am_Wq = (const float*)d_in[15]; p.am_bq = (const float*)d_in[16];
    p.am_Wr = (const float*)d_in[17]; p.am_V  = (const float*)d_in[18];
    p.ja_Wq = (const float*)d_in[19]; p.ja_bq = (const float*)d_in[20];
    p.ja_Wr = (const float*)d_in[21]; p.ja_V  = (const float*)d_in[22];
    p.ma_Wq = (const float*)d_in[23]; p.ma_bq = (const float*)d_in[24];
    p.ma_Wr = (const float*)d_in[25]; p.ma_V  = (const float*)d_in[26];
    p.g1W = (const float*)d_in[27]; p.g1b = (const float*)d_in[28];
    p.g2W = (const float*)d_in[29]; p.g2b = (const float*)d_in[30];
    p.last_j = (const float*)d_in[31];
    p.S   = (float*)d_ws;
    p.cnt = (int*)((float*)d_ws + S_CNT);
    p.Ej  = (float*)d_ws + E_OFF;
    p.Em  = p.Ej + (size_t)NJ * 16;
    p.out = (float*)d_out;

    const size_t needed = (E_OFF + (size_t)(NJ + NM) * 16) * sizeof(float);
    const bool cache = ws_size >= needed;

    // zero the 4 arrive counters (ws is poisoned 0xAA before every launch)
    hipMemsetAsync((void*)p.cnt, 0, 4 * sizeof(int), stream);

    if (cache) {
        k_p1<true><<<G1, BLK, 0, stream>>>(p);
        k_p3<true><<<GJ, BLK, 0, stream>>>(p);
        k_p5<true><<<G1, BLK, 0, stream>>>(p);
        k_p7<true><<<GM, BLK, 0, stream>>>(p);
    } else {
        k_p1<false><<<G1, BLK, 0, stream>>>(p);
        k_p3<false><<<GJ, BLK, 0, stream>>>(p);
        k_p5<false><<<G1, BLK, 0, stream>>>(p);
        k_p7<false><<<GM, BLK, 0, stream>>>(p);
    }
}